// Round 22
// baseline (106.335 us; speedup 1.0000x reference)
//
#include <hip/hip_runtime.h>
#include <hip/hip_bf16.h>
#include <stdint.h>

typedef __attribute__((ext_vector_type(8))) short bf8;
typedef __attribute__((ext_vector_type(4))) float f4;

#define MFMA16(a, b, c) __builtin_amdgcn_mfma_f32_16x16x32_bf16((a), (b), (c), 0, 0, 0)

static __device__ __forceinline__ short f2b(float f) {
  uint32_t x = __float_as_uint(f);
  x += 0x7fffu + ((x >> 16) & 1u);
  return (short)(x >> 16);
}

// single-instruction pack: {bf16(lo), bf16(hi)} -> u32 (RNE)
static __device__ __forceinline__ uint32_t cvtpk(float lo, float hi) {
  uint32_t r;
  asm("v_cvt_pk_bf16_f32 %0, %1, %2" : "=v"(r) : "v"(lo), "v"(hi));
  return r;
}

// async global->LDS, 16B per lane; LDS dest = wave-uniform base + lane*16
static __device__ __forceinline__ void gload16(const short* g, void* l) {
  __builtin_amdgcn_global_load_lds(
      (const __attribute__((address_space(1))) void*)g,
      (__attribute__((address_space(3))) void*)l, 16, 0, 0);
}

// fused: f32->bf16 convert (x -> xb, 4 weights -> Wb) + rope table build.
__global__ void convert_kernel(const float* __restrict__ x,
                               const float* __restrict__ wq, const float* __restrict__ wk,
                               const float* __restrict__ wv, const float* __restrict__ wo,
                               short* __restrict__ xb, short* __restrict__ Wb,
                               float2* __restrict__ tab) {
  const int bid = blockIdx.x;
  if (bid >= 4096) {
    const int t = (bid - 4096) * 256 + threadIdx.x;
    const int s = t >> 5, i = t & 31;
    const float inv = powf(10000.0f, -(float)i * (1.0f / 32.0f));
    const float ang = (float)s * inv;
    float sv, cv;
    sincosf(ang, &sv, &cv);
    tab[t] = make_float2(cv, sv);
    return;
  }
  const size_t i = ((size_t)bid * 256 + threadIdx.x) * 8;
  const float* __restrict__ src;
  short* __restrict__ dst;
  if (i < 4194304u) {
    src = x + i;
    dst = xb + i;
  } else {
    const size_t j = i - 4194304u;
    const int z = (int)(j >> 20);
    const size_t o = j & 1048575u;
    src = (z == 0 ? wq : z == 1 ? wk : z == 2 ? wv : wo) + o;
    dst = Wb + j;
  }
  const float4 a = *(const float4*)src;
  const float4 b = *(const float4*)(src + 4);
  bf8 v;
  v[0] = f2b(a.x); v[1] = f2b(a.y); v[2] = f2b(a.z); v[3] = f2b(a.w);
  v[4] = f2b(b.x); v[5] = f2b(b.y); v[6] = f2b(b.z); v[7] = f2b(b.w);
  *(bf8*)dst = v;
}

// C = A @ W^T, pure-bf16. 128x128 tiles, BK=64 — now 512 threads / 8 waves,
// each wave a 64x32 sub-tile (acc 4x2): same LDS (32KB) and grid, but 2x the
// resident waves per CU (12 -> 24) for the latency-bound 2-barrier schedule.
// Staging: 4 gload16/thread; LDS image byte-identical to the 256-thr version
// (base = wave*1024 + i*8192), so swizzle/fragment math is unchanged.
// MODE 0: W = Wb[blockIdx.z], z<2 -> RoPE Q/K epilogue; z==2 -> V^T epilogue
// MODE 1: W = Wb[3] (Wo), f32 epilogue -> [m][n]
template <int MODE>
__launch_bounds__(512, 2)
__global__ void gemm_kernel(const short* __restrict__ Ab, const short* __restrict__ Wb,
                            short* __restrict__ Qo, short* __restrict__ Ko,
                            short* __restrict__ VTo, float* __restrict__ Fo,
                            const float2* __restrict__ rope) {
  constexpr int K = 1024;
  const int bm = blockIdx.x, bn = blockIdx.y;
  const int z = (MODE == 0) ? blockIdx.z : 3;
  const short* __restrict__ Bb = Wb + ((size_t)z << 20);

  __shared__ short As[128 * 64];
  __shared__ short Bs[128 * 64];

  const int tid = threadIdx.x;
  const int lane = tid & 63;
  const int wave = tid >> 6;          // 0..7
  const int wr = wave >> 2, wc = wave & 3;  // 2 x 4 wave grid
  const int lg = lane >> 4, lr = lane & 15;

  f4 acc[4][2];
#pragma unroll
  for (int i = 0; i < 4; i++)
#pragma unroll
    for (int j = 0; j < 2; j++) {
      acc[i][j][0] = 0.f; acc[i][j][1] = 0.f;
      acc[i][j][2] = 0.f; acc[i][j][3] = 0.f;
    }

  const int kc = tid & 7;
  const int srow = tid >> 3;               // 0..63
  const int kcs = (kc ^ (srow & 7)) * 8;   // inverse-swizzled source chunk
  char* const Asw = (char*)As + wave * 1024;
  char* const Bsw = (char*)Bs + wave * 1024;

  for (int k0 = 0; k0 < K; k0 += 64) {
#pragma unroll
    for (int i = 0; i < 2; i++) {
      const int row = srow + i * 64;
      gload16(Ab + (size_t)(bm * 128 + row) * K + k0 + kcs, Asw + i * 8192);
      gload16(Bb + (size_t)(bn * 128 + row) * K + k0 + kcs, Bsw + i * 8192);
    }
    __syncthreads();
#pragma unroll
    for (int kk = 0; kk < 2; kk++) {
      bf8 af[4], bb[2];
#pragma unroll
      for (int mi = 0; mi < 4; mi++) {
        const int row = wr * 64 + mi * 16 + lr;
        const int lb = (row * 128 + kk * 64 + lg * 16) ^ ((row & 7) << 4);
        af[mi] = *(const bf8*)((const char*)As + lb);
      }
#pragma unroll
      for (int ni = 0; ni < 2; ni++) {
        const int row = wc * 32 + ni * 16 + lr;
        const int lb = (row * 128 + kk * 64 + lg * 16) ^ ((row & 7) << 4);
        bb[ni] = *(const bf8*)((const char*)Bs + lb);
      }
#pragma unroll
      for (int mi = 0; mi < 4; mi++)
#pragma unroll
        for (int ni = 0; ni < 2; ni++)
          acc[mi][ni] = MFMA16(af[mi], bb[ni], acc[mi][ni]);
    }
    __syncthreads();
  }

  if (MODE == 1) {
#pragma unroll
    for (int mi = 0; mi < 4; mi++) {
      const int m0 = bm * 128 + wr * 64 + mi * 16 + lg * 4;
#pragma unroll
      for (int ni = 0; ni < 2; ni++) {
        const int n = bn * 128 + wc * 32 + ni * 16 + lr;
#pragma unroll
        for (int r = 0; r < 4; r++)
          Fo[(size_t)(m0 + r) * 1024 + n] = acc[mi][ni][r];
      }
    }
    return;
  }

  if (z == 2) {  // V^T: [b][h][64][s]
#pragma unroll
    for (int mi = 0; mi < 4; mi++) {
      const int m0 = bm * 128 + wr * 64 + mi * 16 + lg * 4;
      const int b = m0 >> 11, s0 = m0 & 2047;
#pragma unroll
      for (int ni = 0; ni < 2; ni++) {
        const int n = bn * 128 + wc * 32 + ni * 16 + lr;
        ushort4 pk;
        pk.x = (unsigned short)f2b(acc[mi][ni][0]);
        pk.y = (unsigned short)f2b(acc[mi][ni][1]);
        pk.z = (unsigned short)f2b(acc[mi][ni][2]);
        pk.w = (unsigned short)f2b(acc[mi][ni][3]);
        *(ushort4*)(VTo + ((size_t)((b * 16 + (n >> 6)) * 64 + (n & 63))) * 2048 + s0) = pk;
      }
    }
  } else {  // Q or K with RoPE: [b][h][s][64]
    short* __restrict__ Out = (z == 0) ? Qo : Ko;
    // Q gets the attention scale folded with log2(e) so softmax can use exp2
    const float qscale = (z == 0) ? 0.18033688011112042f : 1.0f;  // 0.125*log2(e)
#pragma unroll
    for (int mi = 0; mi < 4; mi++) {
      const int m0 = bm * 128 + wr * 64 + mi * 16 + lg * 4;
      const int b = m0 >> 11, s0 = m0 & 2047;
#pragma unroll
      for (int ni = 0; ni < 2; ni++) {
        const int n = bn * 128 + wc * 32 + ni * 16 + lr;
        const int h = n >> 6, d = n & 63;
        const float sgn = (d & 1) ? 1.0f : -1.0f;
#pragma unroll
        for (int r = 0; r < 4; r++) {
          const float v = acc[mi][ni][r];
          const float p = __shfl_xor(v, 1);
          const float2 cs = rope[((s0 + r) << 5) + (d >> 1)];
          const float res = (v * cs.x + sgn * p * cs.y) * qscale;
          Out[((size_t)(b * 16 + h) * 2048 + (s0 + r)) * 64 + d] = f2b(res);
        }
      }
    }
  }
}

// Flash attention, causal, BK=128 (R20 verbatim — best measured config).
// 8-wave block owns 128 q-rows; per barrier stages K(16KB)+V^T(16KB) for a
// 128-wide KV block; two round-bodies per barrier (32 MFMA/barrier). V
// fragment ds_reads hoisted above softmax (R20 win). nkv = qb+1 uniform.
// Static longest-first grid + XCD-clustered bh. cvt_pk pack, deferred
// cross-lane max, soft ordering.
__launch_bounds__(512, 4)
__global__ void attn_kernel(const short* __restrict__ Qg, const short* __restrict__ Kg,
                            const short* __restrict__ Vg, short* __restrict__ AO) {
  const int S = 2048;
  const int id = blockIdx.x;
  const int xcd = id & 7, slot = id >> 3;
  const int bh = xcd * 4 + (slot & 3);   // XCD-clustered head/batch
  const int qb = 15 - (slot >> 2);       // longest-first
  const int tid = threadIdx.x;
  const int lane = tid & 63, wave = tid >> 6;
  const int lg = lane >> 4, lr = lane & 15;
  const short* __restrict__ Qp = Qg + (size_t)bh * S * 64;
  const short* __restrict__ Kp = Kg + (size_t)bh * S * 64;
  const short* __restrict__ Vp = Vg + (size_t)bh * 64 * S;

  __shared__ short KB[2][2][64 * 64];  // [buf][half] K tile [kv][d], swizzled
  __shared__ short VB[2][2][64 * 64];  // [buf][half] V^T tile [d][kv], swizzled
  __shared__ short PB[8][16 * 64];     // wave-private P tiles

  const int srow = tid >> 3;
  const int kcs = ((tid & 7) ^ (srow & 7)) * 8;

  const int qbase = qb * 128 + wave * 16;
  const int nkv = qb + 1;  // identical for all 8 waves

  bf8 qf[2];
#pragma unroll
  for (int ks = 0; ks < 2; ks++)
    qf[ks] = *(const bf8*)(Qp + (size_t)(qbase + lr) * 64 + ks * 32 + lg * 8);

  f4 o[4];
#pragma unroll
  for (int dt = 0; dt < 4; dt++) {
    o[dt][0] = 0.f; o[dt][1] = 0.f; o[dt][2] = 0.f; o[dt][3] = 0.f;
  }
  float mrun = -1e30f, lsum = 0.f;

  char* const Pw = (char*)&PB[wave][0];
  const int rowoff = lr * 128;
  const int sw = (lr & 7) << 4;

  // prologue: stage KV block 0 (both halves) into buf 0
#pragma unroll
  for (int h = 0; h < 2; h++) {
    gload16(Kp + (size_t)(64 * h + srow) * 64 + kcs, (char*)KB[0][h] + wave * 1024);
    gload16(Vp + (size_t)srow * 2048 + 64 * h + kcs, (char*)VB[0][h] + wave * 1024);
  }
  __syncthreads();

  for (int kb = 0; kb < nkv; kb++) {
    const int kvb = kb * 128;
    const int cur = kb & 1;

    if (kb + 1 < nkv) {  // stage next 128-KV block (hidden under compute)
      const int nb = kvb + 128;
#pragma unroll
      for (int h = 0; h < 2; h++) {
        gload16(Kp + (size_t)(nb + 64 * h + srow) * 64 + kcs, (char*)KB[cur ^ 1][h] + wave * 1024);
        gload16(Vp + (size_t)srow * 2048 + nb + 64 * h + kcs, (char*)VB[cur ^ 1][h] + wave * 1024);
      }
    }

#pragma unroll
    for (int h = 0; h < 2; h++) {
      const int kvbh = kvb + 64 * h;
      if (kvbh < qbase + 16) {  // half active (uniform per wave)
        const char* Kc = (const char*)KB[cur][h];
        const char* Vc = (const char*)VB[cur][h];

        // swapped QK^T: st[nt] = S^T[kv = kvbh+nt*16+lg*4+r][q = qbase+lr]
        f4 st[4];
        __builtin_amdgcn_s_setprio(1);
#pragma unroll
        for (int nt = 0; nt < 4; nt++) {
          const int row = nt * 16 + lr;
          const int base = row * 128 + lg * 16;
          const int rsw = (row & 7) << 4;
          const bf8 k0 = *(const bf8*)(Kc + (base ^ rsw));
          const bf8 k1 = *(const bf8*)(Kc + ((base + 64) ^ rsw));
          f4 c;
          c[0] = 0.f; c[1] = 0.f; c[2] = 0.f; c[3] = 0.f;
          c = MFMA16(k0, qf[0], c);
          c = MFMA16(k1, qf[1], c);
          st[nt] = c;
        }
        __builtin_amdgcn_s_setprio(0);

        // V fragments issued NOW (depend only on the round barrier): their
        // LDS latency hides under the softmax VALU chain below.
        bf8 vf0[4], vf1[4];
#pragma unroll
        for (int dt = 0; dt < 4; dt++) {
          const int row = dt * 16 + lr;
          const int base = row * 128 + lg * 16;
          const int rsw = (row & 7) << 4;
          vf0[dt] = *(const bf8*)(Vc + (base ^ rsw));
          vf1[dt] = *(const bf8*)(Vc + ((base + 64) ^ rsw));
        }

        if ((kvbh + 63) > qbase) {  // causal mask (diagonal block only)
          const int q = qbase + lr;
#pragma unroll
          for (int nt = 0; nt < 4; nt++)
#pragma unroll
            for (int r = 0; r < 4; r++) {
              const int kv = kvbh + nt * 16 + lg * 4 + r;
              if (kv > q) st[nt][r] = -1e9f;
            }
        }

        // in-lane max only (15 ops, no shuffles)
        float m0 = fmaxf(fmaxf(st[0][0], st[0][1]), fmaxf(st[0][2], st[0][3]));
#pragma unroll
        for (int nt = 1; nt < 4; nt++)
          m0 = fmaxf(m0, fmaxf(fmaxf(st[nt][0], st[nt][1]), fmaxf(st[nt][2], st[nt][3])));

        // deferred cross-lane max: local bound test triggers the rare full
        // reduce + rescale (exp2-domain headroom 2^8 as before)
        if (__any(m0 - mrun > 8.0f)) {
          m0 = fmaxf(m0, __shfl_xor(m0, 16));
          m0 = fmaxf(m0, __shfl_xor(m0, 32));
          const float mn = fmaxf(mrun, m0);
          const float corr = __builtin_amdgcn_exp2f(mrun - mn);
          mrun = mn;
          lsum *= corr;
#pragma unroll
          for (int r = 0; r < 4; r++) {
            const float co = __shfl(corr, (lg << 2) + r);  // o-layout q = lg*4+r
#pragma unroll
            for (int dt = 0; dt < 4; dt++) o[dt][r] *= co;
          }
        }

        // WAR order vs previous P reads: compile-barrier only (wave-private
        // P; per-wave LDS pipe is in-order)
        asm volatile("" ::: "memory");

        // P = exp2(st - m); in-lane partial sums; cvt_pk pairs -> b64 store
#pragma unroll
        for (int nt = 0; nt < 4; nt++) {
          const float p0 = __builtin_amdgcn_exp2f(st[nt][0] - mrun);
          const float p1 = __builtin_amdgcn_exp2f(st[nt][1] - mrun);
          const float p2 = __builtin_amdgcn_exp2f(st[nt][2] - mrun);
          const float p3 = __builtin_amdgcn_exp2f(st[nt][3] - mrun);
          lsum += (p0 + p1) + (p2 + p3);
          *(uint2*)(Pw + ((rowoff + nt * 32 + lg * 8) ^ sw)) =
              make_uint2(cvtpk(p0, p1), cvtpk(p2, p3));
        }

        // RAW order: ds_read after ds_write same addr, in-order per wave;
        // compiler inserts the data-wait before the PV MFMAs
        asm volatile("" ::: "memory");

        bf8 pf[2];
#pragma unroll
        for (int ks = 0; ks < 2; ks++)
          pf[ks] = *(const bf8*)(Pw + ((rowoff + ks * 64 + lg * 16) ^ sw));

        __builtin_amdgcn_s_setprio(1);
#pragma unroll
        for (int dt = 0; dt < 4; dt++) {
          o[dt] = MFMA16(pf[0], vf0[dt], o[dt]);
          o[dt] = MFMA16(pf[1], vf1[dt], o[dt]);
        }
        __builtin_amdgcn_s_setprio(0);
      }
    }

    __syncthreads();  // drains vmcnt: next staged buffer complete
  }

  // finalize: cross-lg sum reduce in swapped layout, redistribute 1/lsum
  float s = lsum;
  s += __shfl_xor(s, 16);
  s += __shfl_xor(s, 32);
  const float inv = 1.0f / s;
  float inv_o[4];
#pragma unroll
  for (int r = 0; r < 4; r++) inv_o[r] = __shfl(inv, (lg << 2) + r);

  const int b = bh >> 4, h = bh & 15;
#pragma unroll
  for (int r = 0; r < 4; r++) {
    const int q = qbase + lg * 4 + r;
#pragma unroll
    for (int dt = 0; dt < 4; dt++) {
      const int d = dt * 16 + lr;
      AO[((size_t)b * 2048 + q) * 1024 + h * 64 + d] = f2b(o[dt][r] * inv_o[r]);
    }
  }
}

extern "C" void kernel_launch(void* const* d_in, const int* in_sizes, int n_in,
                              void* d_out, int out_size, void* d_ws, size_t ws_size,
                              hipStream_t stream) {
  const float* x  = (const float*)d_in[0];
  const float* wq = (const float*)d_in[1];
  const float* wk = (const float*)d_in[2];
  const float* wv = (const float*)d_in[3];
  const float* wo = (const float*)d_in[4];
  float* out = (float*)d_out;

  char* ws = (char*)d_ws;
  short*  Qb  = (short*)(ws);                       // 8 MB  [b][h][s][64] bf16 (pre-scaled)
  short*  Kb  = (short*)(ws + (8ull  << 20));       // 8 MB
  short*  VTb = (short*)(ws + (16ull << 20));       // 8 MB  [b][h][64][s] bf16
  short*  AOb = (short*)(ws + (24ull << 20));       // 8 MB  [b][s][1024] bf16 (aliases xb)
  short*  xb  = AOb;                                // xb dead before attn writes AOb
  short*  Wb  = (short*)(ws + (32ull << 20));       // 8 MB  [4][1024][1024] bf16
  float2* tab = (float2*)(ws + (40ull << 20));      // 512 KB rope table

  convert_kernel<<<4352, 256, 0, stream>>>(x, wq, wk, wv, wo, xb, Wb, tab);
  gemm_kernel<0><<<dim3(32, 8, 3), 512, 0, stream>>>(
      xb, Wb, Qb, Kb, VTb, nullptr, tab);
  attn_kernel<<<512, 512, 0, stream>>>(Qb, Kb, VTb, AOb);
  gemm_kernel<1><<<dim3(32, 8, 1), 512, 0, stream>>>(
      AOb, Wb, nullptr, nullptr, nullptr, out, nullptr);
}

// Round 23
// 102.677 us; speedup vs baseline: 1.0356x; 1.0356x over previous
//
#include <hip/hip_runtime.h>
#include <hip/hip_bf16.h>
#include <stdint.h>

typedef __attribute__((ext_vector_type(8))) short bf8;
typedef __attribute__((ext_vector_type(4))) float f4;

#define MFMA16(a, b, c) __builtin_amdgcn_mfma_f32_16x16x32_bf16((a), (b), (c), 0, 0, 0)

static __device__ __forceinline__ short f2b(float f) {
  uint32_t x = __float_as_uint(f);
  x += 0x7fffu + ((x >> 16) & 1u);
  return (short)(x >> 16);
}

// single-instruction pack: {bf16(lo), bf16(hi)} -> u32 (RNE)
static __device__ __forceinline__ uint32_t cvtpk(float lo, float hi) {
  uint32_t r;
  asm("v_cvt_pk_bf16_f32 %0, %1, %2" : "=v"(r) : "v"(lo), "v"(hi));
  return r;
}

// async global->LDS, 16B per lane; LDS dest = wave-uniform base + lane*16
static __device__ __forceinline__ void gload16(const short* g, void* l) {
  __builtin_amdgcn_global_load_lds(
      (const __attribute__((address_space(1))) void*)g,
      (__attribute__((address_space(3))) void*)l, 16, 0, 0);
}

// fused: f32->bf16 convert (x -> xb, 4 weights -> Wb) + rope table build.
__global__ void convert_kernel(const float* __restrict__ x,
                               const float* __restrict__ wq, const float* __restrict__ wk,
                               const float* __restrict__ wv, const float* __restrict__ wo,
                               short* __restrict__ xb, short* __restrict__ Wb,
                               float2* __restrict__ tab) {
  const int bid = blockIdx.x;
  if (bid >= 4096) {
    const int t = (bid - 4096) * 256 + threadIdx.x;
    const int s = t >> 5, i = t & 31;
    const float inv = powf(10000.0f, -(float)i * (1.0f / 32.0f));
    const float ang = (float)s * inv;
    float sv, cv;
    sincosf(ang, &sv, &cv);
    tab[t] = make_float2(cv, sv);
    return;
  }
  const size_t i = ((size_t)bid * 256 + threadIdx.x) * 8;
  const float* __restrict__ src;
  short* __restrict__ dst;
  if (i < 4194304u) {
    src = x + i;
    dst = xb + i;
  } else {
    const size_t j = i - 4194304u;
    const int z = (int)(j >> 20);
    const size_t o = j & 1048575u;
    src = (z == 0 ? wq : z == 1 ? wk : z == 2 ? wv : wo) + o;
    dst = Wb + j;
  }
  const float4 a = *(const float4*)src;
  const float4 b = *(const float4*)(src + 4);
  bf8 v;
  v[0] = f2b(a.x); v[1] = f2b(a.y); v[2] = f2b(a.z); v[3] = f2b(a.w);
  v[4] = f2b(b.x); v[5] = f2b(b.y); v[6] = f2b(b.z); v[7] = f2b(b.w);
  *(bf8*)dst = v;
}

// C = A @ W^T, pure-bf16. 128x128 tiles, BK=64, 4 waves each 64x64.
// R15/R20 2-barrier structure (32KB LDS -> ~5 blocks/CU inter-block overlap;
// explicit dbuf regressed in R17, 8-wave split regressed in R22).
// Staging via global_load_lds (16B) with inverse-swizzled global source
// (rule-21: linear dest + inv-swz source + swz read).
// MODE 0: W = Wb[blockIdx.z], z<2 -> RoPE Q/K epilogue; z==2 -> V^T epilogue
// MODE 1: W = Wb[3] (Wo), f32 epilogue -> [m][n]
template <int MODE>
__launch_bounds__(256, 2)
__global__ void gemm_kernel(const short* __restrict__ Ab, const short* __restrict__ Wb,
                            short* __restrict__ Qo, short* __restrict__ Ko,
                            short* __restrict__ VTo, float* __restrict__ Fo,
                            const float2* __restrict__ rope) {
  constexpr int K = 1024;
  const int bm = blockIdx.x, bn = blockIdx.y;
  const int z = (MODE == 0) ? blockIdx.z : 3;
  const short* __restrict__ Bb = Wb + ((size_t)z << 20);

  __shared__ short As[128 * 64];
  __shared__ short Bs[128 * 64];

  const int tid = threadIdx.x;
  const int lane = tid & 63;
  const int wave = tid >> 6;
  const int wr = wave >> 1, wc = wave & 1;
  const int lg = lane >> 4, lr = lane & 15;

  f4 acc[4][4];
#pragma unroll
  for (int i = 0; i < 4; i++)
#pragma unroll
    for (int j = 0; j < 4; j++) {
      acc[i][j][0] = 0.f; acc[i][j][1] = 0.f;
      acc[i][j][2] = 0.f; acc[i][j][3] = 0.f;
    }

  const int kc = tid & 7;
  const int srow = tid >> 3;
  const int kcs = (kc ^ (srow & 7)) * 8;
  char* const Asw = (char*)As + wave * 1024;
  char* const Bsw = (char*)Bs + wave * 1024;

  for (int k0 = 0; k0 < K; k0 += 64) {
#pragma unroll
    for (int i = 0; i < 4; i++) {
      const int row = srow + i * 32;
      gload16(Ab + (size_t)(bm * 128 + row) * K + k0 + kcs, Asw + i * 4096);
      gload16(Bb + (size_t)(bn * 128 + row) * K + k0 + kcs, Bsw + i * 4096);
    }
    __syncthreads();
#pragma unroll
    for (int kk = 0; kk < 2; kk++) {
      bf8 af[4], bb[4];
#pragma unroll
      for (int mi = 0; mi < 4; mi++) {
        const int row = wr * 64 + mi * 16 + lr;
        const int lb = (row * 128 + kk * 64 + lg * 16) ^ ((row & 7) << 4);
        af[mi] = *(const bf8*)((const char*)As + lb);
      }
#pragma unroll
      for (int ni = 0; ni < 4; ni++) {
        const int row = wc * 64 + ni * 16 + lr;
        const int lb = (row * 128 + kk * 64 + lg * 16) ^ ((row & 7) << 4);
        bb[ni] = *(const bf8*)((const char*)Bs + lb);
      }
#pragma unroll
      for (int mi = 0; mi < 4; mi++)
#pragma unroll
        for (int ni = 0; ni < 4; ni++)
          acc[mi][ni] = MFMA16(af[mi], bb[ni], acc[mi][ni]);
    }
    __syncthreads();
  }

  if (MODE == 1) {
#pragma unroll
    for (int mi = 0; mi < 4; mi++) {
      const int m0 = bm * 128 + wr * 64 + mi * 16 + lg * 4;
#pragma unroll
      for (int ni = 0; ni < 4; ni++) {
        const int n = bn * 128 + wc * 64 + ni * 16 + lr;
#pragma unroll
        for (int r = 0; r < 4; r++)
          Fo[(size_t)(m0 + r) * 1024 + n] = acc[mi][ni][r];
      }
    }
    return;
  }

  if (z == 2) {  // V^T: [b][h][64][s]
#pragma unroll
    for (int mi = 0; mi < 4; mi++) {
      const int m0 = bm * 128 + wr * 64 + mi * 16 + lg * 4;
      const int b = m0 >> 11, s0 = m0 & 2047;
#pragma unroll
      for (int ni = 0; ni < 4; ni++) {
        const int n = bn * 128 + wc * 64 + ni * 16 + lr;
        ushort4 pk;
        pk.x = (unsigned short)f2b(acc[mi][ni][0]);
        pk.y = (unsigned short)f2b(acc[mi][ni][1]);
        pk.z = (unsigned short)f2b(acc[mi][ni][2]);
        pk.w = (unsigned short)f2b(acc[mi][ni][3]);
        *(ushort4*)(VTo + ((size_t)((b * 16 + (n >> 6)) * 64 + (n & 63))) * 2048 + s0) = pk;
      }
    }
  } else {  // Q or K with RoPE: [b][h][s][64]
    short* __restrict__ Out = (z == 0) ? Qo : Ko;
    // Q gets the attention scale folded with log2(e) so softmax can use exp2
    const float qscale = (z == 0) ? 0.18033688011112042f : 1.0f;  // 0.125*log2(e)
#pragma unroll
    for (int mi = 0; mi < 4; mi++) {
      const int m0 = bm * 128 + wr * 64 + mi * 16 + lg * 4;
      const int b = m0 >> 11, s0 = m0 & 2047;
#pragma unroll
      for (int ni = 0; ni < 4; ni++) {
        const int n = bn * 128 + wc * 64 + ni * 16 + lr;
        const int h = n >> 6, d = n & 63;
        const float sgn = (d & 1) ? 1.0f : -1.0f;
#pragma unroll
        for (int r = 0; r < 4; r++) {
          const float v = acc[mi][ni][r];
          const float p = __shfl_xor(v, 1);
          const float2 cs = rope[((s0 + r) << 5) + (d >> 1)];
          const float res = (v * cs.x + sgn * p * cs.y) * qscale;
          Out[((size_t)(b * 16 + h) * 2048 + (s0 + r)) * 64 + d] = f2b(res);
        }
      }
    }
  }
}

// Flash attention, causal, BK=128 (R20 verbatim — best measured config).
// 8-wave block owns 128 q-rows; per barrier stages K(16KB)+V^T(16KB) for a
// 128-wide KV block; two round-bodies per barrier (32 MFMA/barrier). V
// fragment ds_reads hoisted above softmax (R20 win). nkv = qb+1 uniform.
// Static longest-first grid + XCD-clustered bh. cvt_pk pack, deferred
// cross-lane max, soft ordering.
__launch_bounds__(512, 4)
__global__ void attn_kernel(const short* __restrict__ Qg, const short* __restrict__ Kg,
                            const short* __restrict__ Vg, short* __restrict__ AO) {
  const int S = 2048;
  const int id = blockIdx.x;
  const int xcd = id & 7, slot = id >> 3;
  const int bh = xcd * 4 + (slot & 3);   // XCD-clustered head/batch
  const int qb = 15 - (slot >> 2);       // longest-first
  const int tid = threadIdx.x;
  const int lane = tid & 63, wave = tid >> 6;
  const int lg = lane >> 4, lr = lane & 15;
  const short* __restrict__ Qp = Qg + (size_t)bh * S * 64;
  const short* __restrict__ Kp = Kg + (size_t)bh * S * 64;
  const short* __restrict__ Vp = Vg + (size_t)bh * 64 * S;

  __shared__ short KB[2][2][64 * 64];  // [buf][half] K tile [kv][d], swizzled
  __shared__ short VB[2][2][64 * 64];  // [buf][half] V^T tile [d][kv], swizzled
  __shared__ short PB[8][16 * 64];     // wave-private P tiles

  const int srow = tid >> 3;
  const int kcs = ((tid & 7) ^ (srow & 7)) * 8;

  const int qbase = qb * 128 + wave * 16;
  const int nkv = qb + 1;  // identical for all 8 waves

  bf8 qf[2];
#pragma unroll
  for (int ks = 0; ks < 2; ks++)
    qf[ks] = *(const bf8*)(Qp + (size_t)(qbase + lr) * 64 + ks * 32 + lg * 8);

  f4 o[4];
#pragma unroll
  for (int dt = 0; dt < 4; dt++) {
    o[dt][0] = 0.f; o[dt][1] = 0.f; o[dt][2] = 0.f; o[dt][3] = 0.f;
  }
  float mrun = -1e30f, lsum = 0.f;

  char* const Pw = (char*)&PB[wave][0];
  const int rowoff = lr * 128;
  const int sw = (lr & 7) << 4;

  // prologue: stage KV block 0 (both halves) into buf 0
#pragma unroll
  for (int h = 0; h < 2; h++) {
    gload16(Kp + (size_t)(64 * h + srow) * 64 + kcs, (char*)KB[0][h] + wave * 1024);
    gload16(Vp + (size_t)srow * 2048 + 64 * h + kcs, (char*)VB[0][h] + wave * 1024);
  }
  __syncthreads();

  for (int kb = 0; kb < nkv; kb++) {
    const int kvb = kb * 128;
    const int cur = kb & 1;

    if (kb + 1 < nkv) {  // stage next 128-KV block (hidden under compute)
      const int nb = kvb + 128;
#pragma unroll
      for (int h = 0; h < 2; h++) {
        gload16(Kp + (size_t)(nb + 64 * h + srow) * 64 + kcs, (char*)KB[cur ^ 1][h] + wave * 1024);
        gload16(Vp + (size_t)srow * 2048 + nb + 64 * h + kcs, (char*)VB[cur ^ 1][h] + wave * 1024);
      }
    }

#pragma unroll
    for (int h = 0; h < 2; h++) {
      const int kvbh = kvb + 64 * h;
      if (kvbh < qbase + 16) {  // half active (uniform per wave)
        const char* Kc = (const char*)KB[cur][h];
        const char* Vc = (const char*)VB[cur][h];

        // swapped QK^T: st[nt] = S^T[kv = kvbh+nt*16+lg*4+r][q = qbase+lr]
        f4 st[4];
        __builtin_amdgcn_s_setprio(1);
#pragma unroll
        for (int nt = 0; nt < 4; nt++) {
          const int row = nt * 16 + lr;
          const int base = row * 128 + lg * 16;
          const int rsw = (row & 7) << 4;
          const bf8 k0 = *(const bf8*)(Kc + (base ^ rsw));
          const bf8 k1 = *(const bf8*)(Kc + ((base + 64) ^ rsw));
          f4 c;
          c[0] = 0.f; c[1] = 0.f; c[2] = 0.f; c[3] = 0.f;
          c = MFMA16(k0, qf[0], c);
          c = MFMA16(k1, qf[1], c);
          st[nt] = c;
        }
        __builtin_amdgcn_s_setprio(0);

        // V fragments issued NOW (depend only on the round barrier): their
        // LDS latency hides under the softmax VALU chain below.
        bf8 vf0[4], vf1[4];
#pragma unroll
        for (int dt = 0; dt < 4; dt++) {
          const int row = dt * 16 + lr;
          const int base = row * 128 + lg * 16;
          const int rsw = (row & 7) << 4;
          vf0[dt] = *(const bf8*)(Vc + (base ^ rsw));
          vf1[dt] = *(const bf8*)(Vc + ((base + 64) ^ rsw));
        }

        if ((kvbh + 63) > qbase) {  // causal mask (diagonal block only)
          const int q = qbase + lr;
#pragma unroll
          for (int nt = 0; nt < 4; nt++)
#pragma unroll
            for (int r = 0; r < 4; r++) {
              const int kv = kvbh + nt * 16 + lg * 4 + r;
              if (kv > q) st[nt][r] = -1e9f;
            }
        }

        // in-lane max only (15 ops, no shuffles)
        float m0 = fmaxf(fmaxf(st[0][0], st[0][1]), fmaxf(st[0][2], st[0][3]));
#pragma unroll
        for (int nt = 1; nt < 4; nt++)
          m0 = fmaxf(m0, fmaxf(fmaxf(st[nt][0], st[nt][1]), fmaxf(st[nt][2], st[nt][3])));

        // deferred cross-lane max: local bound test triggers the rare full
        // reduce + rescale (exp2-domain headroom 2^8 as before)
        if (__any(m0 - mrun > 8.0f)) {
          m0 = fmaxf(m0, __shfl_xor(m0, 16));
          m0 = fmaxf(m0, __shfl_xor(m0, 32));
          const float mn = fmaxf(mrun, m0);
          const float corr = __builtin_amdgcn_exp2f(mrun - mn);
          mrun = mn;
          lsum *= corr;
#pragma unroll
          for (int r = 0; r < 4; r++) {
            const float co = __shfl(corr, (lg << 2) + r);  // o-layout q = lg*4+r
#pragma unroll
            for (int dt = 0; dt < 4; dt++) o[dt][r] *= co;
          }
        }

        // WAR order vs previous P reads: compile-barrier only (wave-private
        // P; per-wave LDS pipe is in-order)
        asm volatile("" ::: "memory");

        // P = exp2(st - m); in-lane partial sums; cvt_pk pairs -> b64 store
#pragma unroll
        for (int nt = 0; nt < 4; nt++) {
          const float p0 = __builtin_amdgcn_exp2f(st[nt][0] - mrun);
          const float p1 = __builtin_amdgcn_exp2f(st[nt][1] - mrun);
          const float p2 = __builtin_amdgcn_exp2f(st[nt][2] - mrun);
          const float p3 = __builtin_amdgcn_exp2f(st[nt][3] - mrun);
          lsum += (p0 + p1) + (p2 + p3);
          *(uint2*)(Pw + ((rowoff + nt * 32 + lg * 8) ^ sw)) =
              make_uint2(cvtpk(p0, p1), cvtpk(p2, p3));
        }

        // RAW order: ds_read after ds_write same addr, in-order per wave;
        // compiler inserts the data-wait before the PV MFMAs
        asm volatile("" ::: "memory");

        bf8 pf[2];
#pragma unroll
        for (int ks = 0; ks < 2; ks++)
          pf[ks] = *(const bf8*)(Pw + ((rowoff + ks * 64 + lg * 16) ^ sw));

        __builtin_amdgcn_s_setprio(1);
#pragma unroll
        for (int dt = 0; dt < 4; dt++) {
          o[dt] = MFMA16(pf[0], vf0[dt], o[dt]);
          o[dt] = MFMA16(pf[1], vf1[dt], o[dt]);
        }
        __builtin_amdgcn_s_setprio(0);
      }
    }

    __syncthreads();  // drains vmcnt: next staged buffer complete
  }

  // finalize: cross-lg sum reduce in swapped layout, redistribute 1/lsum
  float s = lsum;
  s += __shfl_xor(s, 16);
  s += __shfl_xor(s, 32);
  const float inv = 1.0f / s;
  float inv_o[4];
#pragma unroll
  for (int r = 0; r < 4; r++) inv_o[r] = __shfl(inv, (lg << 2) + r);

  const int b = bh >> 4, h = bh & 15;
#pragma unroll
  for (int r = 0; r < 4; r++) {
    const int q = qbase + lg * 4 + r;
#pragma unroll
    for (int dt = 0; dt < 4; dt++) {
      const int d = dt * 16 + lr;
      AO[((size_t)b * 2048 + q) * 1024 + h * 64 + d] = f2b(o[dt][r] * inv_o[r]);
    }
  }
}

extern "C" void kernel_launch(void* const* d_in, const int* in_sizes, int n_in,
                              void* d_out, int out_size, void* d_ws, size_t ws_size,
                              hipStream_t stream) {
  const float* x  = (const float*)d_in[0];
  const float* wq = (const float*)d_in[1];
  const float* wk = (const float*)d_in[2];
  const float* wv = (const float*)d_in[3];
  const float* wo = (const float*)d_in[4];
  float* out = (float*)d_out;

  char* ws = (char*)d_ws;
  short*  Qb  = (short*)(ws);                       // 8 MB  [b][h][s][64] bf16 (pre-scaled)
  short*  Kb  = (short*)(ws + (8ull  << 20));       // 8 MB
  short*  VTb = (short*)(ws + (16ull << 20));       // 8 MB  [b][h][64][s] bf16
  short*  AOb = (short*)(ws + (24ull << 20));       // 8 MB  [b][s][1024] bf16 (aliases xb)
  short*  xb  = AOb;                                // xb dead before attn writes AOb
  short*  Wb  = (short*)(ws + (32ull << 20));       // 8 MB  [4][1024][1024] bf16
  float2* tab = (float2*)(ws + (40ull << 20));      // 512 KB rope table

  convert_kernel<<<4352, 256, 0, stream>>>(x, wq, wk, wv, wo, xb, Wb, tab);
  gemm_kernel<0><<<dim3(32, 8, 3), 256, 0, stream>>>(
      xb, Wb, Qb, Kb, VTb, nullptr, tab);
  attn_kernel<<<512, 512, 0, stream>>>(Qb, Kb, VTb, AOb);
  gemm_kernel<1><<<dim3(32, 8, 1), 256, 0, stream>>>(
      AOb, Wb, nullptr, nullptr, nullptr, out, nullptr);
}